// Round 4
// baseline (8583.588 us; speedup 1.0000x reference)
//
#include <hip/hip_runtime.h>

#define NSTEP 64

typedef short bf8 __attribute__((ext_vector_type(8)));          // 8 x bf16 (4 VGPRs) MFMA A/B frag
typedef float f32x16 __attribute__((ext_vector_type(16)));
typedef float f32x4 __attribute__((ext_vector_type(4)));        // 16x16 MFMA C/D frag
typedef float f32x2 __attribute__((ext_vector_type(2)));
typedef unsigned int u32x4 __attribute__((ext_vector_type(4)));
typedef unsigned int u32x2 __attribute__((ext_vector_type(2)));

static __device__ __forceinline__ float asf(unsigned int u){ return __builtin_bit_cast(float, u); }
static __device__ __forceinline__ unsigned int asu(float f){ return __builtin_bit_cast(unsigned int, f); }

// fp32 pair -> packed bf16 dword (RNE, a in low 16)
#if defined(__has_builtin)
#if __has_builtin(__builtin_amdgcn_cvt_pk_bf16_f32)
#define HAVE_CVT_PK_BF16 1
#endif
#endif
#ifdef HAVE_CVT_PK_BF16
typedef __bf16 bf16x2_t __attribute__((ext_vector_type(2)));
static __device__ __forceinline__ unsigned int pk(float a, float b){
  bf16x2_t r = __builtin_amdgcn_cvt_pk_bf16_f32(a, b);
  return __builtin_bit_cast(unsigned int, r);
}
#else
static __device__ __forceinline__ unsigned int pk(float a, float b){
  unsigned int ua = asu(a); unsigned int ub = asu(b);
  ua += 0x7FFFu + ((ua >> 16) & 1u);
  ub += 0x7FFFu + ((ub >> 16) & 1u);
  return (ua >> 16) | (ub & 0xFFFF0000u);
}
#endif

// bf16 round of a f32 (matches what pk feeds the MFMA)
static __device__ __forceinline__ float bfr(float w){ return asf(pk(w, 0.0f) << 16); }

// packed 2xf32 math: compiler emits v_pk_* on gfx90a+
static __device__ __forceinline__ f32x2 pkfma(f32x2 a, f32x2 b, f32x2 c){
  return __builtin_elementwise_fma(a, b, c);
}

static __device__ __forceinline__ f32x2 pairof(const f32x16& v, int j){
  f32x2 r; r.x = v[2*j]; r.y = v[2*j+1]; return r;
}
static __device__ __forceinline__ void setpair(f32x16& v, int j, f32x2 p){
  v[2*j] = p.x; v[2*j+1] = p.y;
}

// scale 8 packed bf16 by s (one-time weight prep)
static __device__ __forceinline__ bf8 scale_bf8(bf8 w, float s){
  u32x4 u = __builtin_bit_cast(u32x4, w);
  u32x4 r;
  #pragma unroll
  for(int i=0;i<4;i++){
    float lo = asf(u[i] << 16) * s;
    float hi = asf(u[i] & 0xFFFF0000u) * s;
    r[i] = pk(lo, hi);
  }
  return __builtin_bit_cast(bf8, r);
}

#define MFMA16 __builtin_amdgcn_mfma_f32_16x16x32_bf16

// ---- k-permuted fragments (verified R3): ZERO cross-lane ops --------------
// MFMA contracts fixed slots (lane-group g, reg j). Same bijection pi(g,j)->k
// applied to A and B leaves the result unchanged:
//   j<4 : k = t0_base + 4g + j ; j>=4: k = t1_base + 4g + (j-4)
// -> B-frag is the natural post-GEMM C-layout, weights loaded with the
//    matching column permutation (two 8B loads per frag).

// Shifted ELU on a 16x16 C-frag (4 elems): GEMM1 gives q = p*log2e (weights pre-scaled).
// h' = h+1 = max(q,0)*ln2 + exp2(min(q,0)); +1 shift compensated in b2' = b2 - rowsum(bf16 W2).
#define ELU2(A, H0, H1) { \
  f32x2 q0; q0.x=A[0]; q0.y=A[1]; \
  f32x2 q1; q1.x=A[2]; q1.y=A[3]; \
  f32x2 m0 = __builtin_elementwise_max(q0, Z2); \
  f32x2 n0 = __builtin_elementwise_min(q0, Z2); \
  f32x2 m1 = __builtin_elementwise_max(q1, Z2); \
  f32x2 n1 = __builtin_elementwise_min(q1, Z2); \
  f32x2 e0; e0.x=__builtin_amdgcn_exp2f(n0.x); e0.y=__builtin_amdgcn_exp2f(n0.y); \
  f32x2 e1; e1.x=__builtin_amdgcn_exp2f(n1.x); e1.y=__builtin_amdgcn_exp2f(n1.y); \
  f32x2 h0 = pkfma(m0, LN22, e0); \
  f32x2 h1 = pkfma(m1, LN22, e1); \
  H0 = pk(h0.x, h0.y); H1 = pk(h1.x, h1.y); \
}

// z-pack for one problem: z = Y + c*K (s==0: z = Y) -> 2 k-permuted B-frags
#define PACKZ(S, Y_, C2_, ZF0, ZF1) \
  bf8 ZF0, ZF1; { \
    unsigned int P[8]; \
    _Pragma("unroll") \
    for(int j=0;j<8;j++){ \
      f32x2 z; \
      if((S)==0){ z = pairof(Y_, j); } \
      else { const f32x2 cc = ((S)==3) ? DT2 : HDT2; \
             z = pkfma(cc, pairof(C2_, j), pairof(Y_, j)); } \
      P[j] = pk(z.x, z.y); \
    } \
    u32x4 u0; u0[0]=P[0]; u0[1]=P[1]; u0[2]=P[2]; u0[3]=P[3]; \
    u32x4 u1; u1[0]=P[4]; u1[1]=P[5]; u1[2]=P[6]; u1[3]=P[7]; \
    ZF0 = __builtin_bit_cast(bf8, u0); \
    ZF1 = __builtin_bit_cast(bf8, u1); \
  }

// One chunk = 32 hidden units for one problem (GEMM1 tile pair -> ELU -> GEMM2 k-step KT).
// Bias seeds come from registers (b1r), not LDS.
#define CHUNK(KT, ZF0, ZF1, P2) { \
  f32x4 a0 = b1r[2*(KT)]; \
  f32x4 a1 = b1r[2*(KT)+1]; \
  a0 = MFMA16(W1f[2*(KT)  ][0], ZF0, a0, 0,0,0); \
  a0 = MFMA16(W1f[2*(KT)  ][1], ZF1, a0, 0,0,0); \
  a1 = MFMA16(W1f[2*(KT)+1][0], ZF0, a1, 0,0,0); \
  a1 = MFMA16(W1f[2*(KT)+1][1], ZF1, a1, 0,0,0); \
  unsigned int H00,H01,H10,H11; \
  ELU2(a0, H00, H01) \
  ELU2(a1, H10, H11) \
  u32x4 hu; hu[0]=H00; hu[1]=H01; hu[2]=H10; hu[3]=H11; \
  bf8 hf = __builtin_bit_cast(bf8, hu); \
  P2[0] = MFMA16(W2f[0][KT], hf, P2[0], 0,0,0); \
  P2[1] = MFMA16(W2f[1][KT], hf, P2[1], 0,0,0); \
  P2[2] = MFMA16(W2f[2][KT], hf, P2[2], 0,0,0); \
  P2[3] = MFMA16(W2f[3][KT], hf, P2[3], 0,0,0); \
}

// RK accumulate: s0: A = k1; s1,s2: A += 2k; s3: A += k4
#define RKACC(S, A_, C2_) \
  _Pragma("unroll") \
  for(int j=0;j<8;j++){ \
    if((S)==0)      setpair(A_, j, pairof(C2_, j)); \
    else if((S)==3) setpair(A_, j, pairof(A_, j) + pairof(C2_, j)); \
    else            setpair(A_, j, pkfma(TWO2, pairof(C2_, j), pairof(A_, j))); \
  }

// Block = 128 threads = 2 waves sharing TWO 16-row batch groups (A: rows 0-15,
// B: rows 16-31 of the block's 32-row slice). Wave wv owns hidden [wv*128,+128)
// for both problems. The A/B interleave supplies in-wave ILP (we run at
// 1 wave/SIMD, ~330 regs); one barrier per stage serves both problems.
// b1/b2' seeds live in registers -> DS ops per stage drop 40 -> 16.
__global__ __launch_bounds__(128, 1) void ode_kernel(
    const void* __restrict__ xv,
    const void* __restrict__ tv,
    const void* __restrict__ W1v,
    const void* __restrict__ b1v,
    const void* __restrict__ W2v,
    const void* __restrict__ b2v,
    void* __restrict__ outv)
{
  __shared__ __align__(16) float b1s[256];
  __shared__ __align__(16) float b2s[64];
  __shared__ __align__(16) float xbuf[2][2][2][1024]; // [parity][wave][problem][4 tiles*64 lanes*4]

  const int tid = threadIdx.x;     // 0..127
  const int lid = tid & 63;        // lane in wave
  const int wv  = tid >> 6;        // wave in pair: hidden-half owner

  // ---- runtime input-dtype detection (wave-uniform; both waves identical) ----
  const unsigned int* w1u = (const unsigned int*)W1v;
  bool bad = false;
  #pragma unroll
  for(int i=0; i<2; i++){
    unsigned int d = w1u[i*64 + lid];
    unsigned int e0 = (d >> 7)  & 0xFFu;
    unsigned int e1 = (d >> 23) & 0xFFu;
    bad |= (e0 >= 125u) || (e1 >= 125u);
  }
  const bool f32in = (__ballot(bad) != 0ull);

  const float L2E = 1.4426950408889634f;

  // ---- biases to LDS (staging only): b1' = b1*log2e ; b2' = (b2 - rowsum(bf16 W2))*0.5 ----
  if(f32in){
    #pragma unroll
    for(int i=0; i<2; i++) b1s[tid + i*128] = ((const float*)b1v)[tid + i*128] * L2E;
  } else {
    #pragma unroll
    for(int i=0; i<2; i++)
      b1s[tid + i*128] = asf((unsigned int)((const unsigned short*)b1v)[tid + i*128] << 16) * L2E;
  }
  if(tid < 64){
    float ssum = 0.0f;
    if(f32in){
      const float* W2 = (const float*)W2v + tid*256;
      #pragma unroll 4
      for(int k=0; k<64; k++){
        f32x4 w4 = *(const f32x4*)(W2 + k*4);
        ssum += bfr(w4[0]) + bfr(w4[1]) + bfr(w4[2]) + bfr(w4[3]);
      }
    } else {
      const unsigned short* W2 = (const unsigned short*)W2v + tid*256;
      for(int k=0; k<256; k++) ssum += asf((unsigned int)W2[k] << 16);
    }
    float bb = f32in ? ((const float*)b2v)[tid]
                     : asf((unsigned int)((const unsigned short*)b2v)[tid] << 16);
    b2s[tid] = (bb - ssum) * 0.5f;   // both waves seed with half
  }
  __syncthreads();

  const int ln = lid & 15;         // MFMA m/n index = batch row within group
  const int g  = lid >> 4;         // lane group 0..3 (k-group / C row group)
  const int g4 = g * 4;
  const int rA = blockIdx.x * 32 + ln;   // problem A global batch row
  const int rB = rA + 16;                // problem B global batch row

  const float t  = f32in ? ((const float*)tv)[0]
                         : asf((unsigned int)((const unsigned short*)tv)[0] << 16);
  const float dt  = t / (float)NSTEP;
  const float hdt = 0.5f * dt;
  const float gg  = dt * (1.0f/6.0f);
  const f32x2 DT2  = {dt, dt};
  const f32x2 HDT2 = {hdt, hdt};
  const f32x2 TWO2 = {2.0f, 2.0f};
  const f32x2 G2   = {gg, gg};
  const f32x2 LN22 = {0.6931471805599453f, 0.6931471805599453f};
  const f32x2 Z2   = {0.0f, 0.0f};

  // ---- bias seeds hoisted to registers (were 12 DS reads per stage) ----
  f32x4 b1r[8];   // GEMM1 seeds: tile tl of this wave's 128 hidden
  #pragma unroll
  for(int tl=0; tl<8; tl++) b1r[tl] = *(const f32x4*)&b1s[wv*128 + tl*16 + g4];
  f32x4 b2r[4];   // GEMM2 seeds (b2'/2)
  #pragma unroll
  for(int mt=0; mt<4; mt++) b2r[mt] = *(const f32x4*)&b2s[mt*16 + g4];

  // ---- weight A-fragments with the k-permutation; W1 pre-scaled by log2e ----
  bf8 W1f[8][2];   // [mtl: 16-row hidden tile within this wave's 128][ks: two 32-feat k-steps]
  bf8 W2f[4][4];   // [mt: 16-row out tile][kt: four 32-hidden k-steps of this wave's half]
  if(f32in){
    const float* W1 = (const float*)W1v;
    const float* W2 = (const float*)W2v;
    #pragma unroll
    for(int mtl=0; mtl<8; mtl++){
      #pragma unroll
      for(int ks=0; ks<2; ks++){
        const float* p = W1 + (wv*128 + mtl*16 + ln)*64 + ks*32 + g4;
        f32x4 a = *(const f32x4*)p;          // feats base+4g..+3   (slots j=0..3)
        f32x4 b = *(const f32x4*)(p + 16);   // feats base+16+4g..  (slots j=4..7)
        u32x4 u;
        u[0]=pk(a[0]*L2E, a[1]*L2E); u[1]=pk(a[2]*L2E, a[3]*L2E);
        u[2]=pk(b[0]*L2E, b[1]*L2E); u[3]=pk(b[2]*L2E, b[3]*L2E);
        W1f[mtl][ks] = __builtin_bit_cast(bf8, u);
      }
    }
    #pragma unroll
    for(int mt=0; mt<4; mt++){
      #pragma unroll
      for(int kt=0; kt<4; kt++){
        const float* p = W2 + (mt*16 + ln)*256 + wv*128 + kt*32 + g4;
        f32x4 a = *(const f32x4*)p;
        f32x4 b = *(const f32x4*)(p + 16);
        u32x4 u; u[0]=pk(a[0],a[1]); u[1]=pk(a[2],a[3]); u[2]=pk(b[0],b[1]); u[3]=pk(b[2],b[3]);
        W2f[mt][kt] = __builtin_bit_cast(bf8, u);
      }
    }
  } else {
    const unsigned short* W1 = (const unsigned short*)W1v;
    const unsigned short* W2 = (const unsigned short*)W2v;
    #pragma unroll
    for(int mtl=0; mtl<8; mtl++){
      #pragma unroll
      for(int ks=0; ks<2; ks++){
        const unsigned short* p = W1 + (wv*128 + mtl*16 + ln)*64 + ks*32 + g4;
        u32x2 lo = *(const u32x2*)p;         // feats base+4g..+3
        u32x2 hi = *(const u32x2*)(p + 16);  // feats base+16+4g..
        u32x4 u; u[0]=lo[0]; u[1]=lo[1]; u[2]=hi[0]; u[3]=hi[1];
        W1f[mtl][ks] = scale_bf8(__builtin_bit_cast(bf8, u), L2E);
      }
    }
    #pragma unroll
    for(int mt=0; mt<4; mt++){
      #pragma unroll
      for(int kt=0; kt<4; kt++){
        const unsigned short* p = W2 + (mt*16 + ln)*256 + wv*128 + kt*32 + g4;
        u32x2 lo = *(const u32x2*)p;
        u32x2 hi = *(const u32x2*)(p + 16);
        u32x4 u; u[0]=lo[0]; u[1]=lo[1]; u[2]=hi[0]; u[3]=hi[1];
        W2f[mt][kt] = __builtin_bit_cast(bf8, u);
      }
    }
  }

  // ---- states Y in 16x16 C-layout: Y[4*mt+i] = y[r][mt*16 + g*4 + i] ----
  f32x16 YA, YB;
  if(f32in){
    const float* x = (const float*)xv;
    #pragma unroll
    for(int mt=0; mt<4; mt++){
      f32x4 vA = *(const f32x4*)(x + rA*64 + mt*16 + g4);
      f32x4 vB = *(const f32x4*)(x + rB*64 + mt*16 + g4);
      #pragma unroll
      for(int i=0;i<4;i++){ YA[4*mt+i] = vA[i]; YB[4*mt+i] = vB[i]; }
    }
  } else {
    const unsigned short* x = (const unsigned short*)xv;
    #pragma unroll
    for(int mt=0; mt<4; mt++){
      u32x2 vA = *(const u32x2*)(x + rA*64 + mt*16 + g4);
      u32x2 vB = *(const u32x2*)(x + rB*64 + mt*16 + g4);
      YA[4*mt+0]=asf(vA[0]<<16); YA[4*mt+1]=asf(vA[0]&0xFFFF0000u);
      YA[4*mt+2]=asf(vA[1]<<16); YA[4*mt+3]=asf(vA[1]&0xFFFF0000u);
      YB[4*mt+0]=asf(vB[0]<<16); YB[4*mt+1]=asf(vB[0]&0xFFFF0000u);
      YB[4*mt+2]=asf(vB[1]<<16); YB[4*mt+3]=asf(vB[1]&0xFFFF0000u);
    }
  }

  f32x16 c2A, c2B;   // full k of previous stage (post-exchange)
  #pragma unroll
  for(int i=0;i<16;i++){ c2A[i]=0.0f; c2B[i]=0.0f; }

  int par = 0;

  #pragma unroll 1
  for(int step=0; step<NSTEP; step++){
    f32x16 AA, AB;   // RK4 accumulators: s0 writes them fully (A = k1)

    #pragma unroll
    for(int s=0; s<4; s++){
      PACKZ(s, YA, c2A, zfA0, zfA1)
      PACKZ(s, YB, c2B, zfB0, zfB1)

      f32x4 p2A[4], p2B[4];
      #pragma unroll
      for(int mt=0; mt<4; mt++){ p2A[mt] = b2r[mt]; p2B[mt] = b2r[mt]; }

      // A/B interleaved: every chain has an independent twin to hide under
      CHUNK(0, zfA0, zfA1, p2A) CHUNK(0, zfB0, zfB1, p2B)
      CHUNK(1, zfA0, zfA1, p2A) CHUNK(1, zfB0, zfB1, p2B)
      CHUNK(2, zfA0, zfA1, p2A) CHUNK(2, zfB0, zfB1, p2B)
      CHUNK(3, zfA0, zfA1, p2A) CHUNK(3, zfB0, zfB1, p2B)

      // ---- sum partials across the wave pair via LDS (parity buffer, 1 barrier) ----
      {
        float* myA = &xbuf[par][wv][0][0];
        float* myB = &xbuf[par][wv][1][0];
        #pragma unroll
        for(int mt=0; mt<4; mt++){
          *(f32x4*)&myA[(mt*64 + lid)*4] = p2A[mt];
          *(f32x4*)&myB[(mt*64 + lid)*4] = p2B[mt];
        }
        __syncthreads();
        const float* prA = &xbuf[par][1-wv][0][0];
        const float* prB = &xbuf[par][1-wv][1][0];
        #pragma unroll
        for(int mt=0; mt<4; mt++){
          f32x4 vA = *(const f32x4*)&prA[(mt*64 + lid)*4];
          f32x4 vB = *(const f32x4*)&prB[(mt*64 + lid)*4];
          f32x2 a0; a0.x = p2A[mt][0]+vA[0]; a0.y = p2A[mt][1]+vA[1];
          f32x2 a1; a1.x = p2A[mt][2]+vA[2]; a1.y = p2A[mt][3]+vA[3];
          setpair(c2A, 2*mt,   a0);
          setpair(c2A, 2*mt+1, a1);
          f32x2 b0; b0.x = p2B[mt][0]+vB[0]; b0.y = p2B[mt][1]+vB[1];
          f32x2 b1x; b1x.x = p2B[mt][2]+vB[2]; b1x.y = p2B[mt][3]+vB[3];
          setpair(c2B, 2*mt,   b0);
          setpair(c2B, 2*mt+1, b1x);
        }
        par ^= 1;
      }

      RKACC(s, AA, c2A)
      RKACC(s, AB, c2B)
    }

    // Y += dt/6 * A
    #pragma unroll
    for(int j=0;j<8;j++){
      setpair(YA, j, pkfma(G2, pairof(AA, j), pairof(YA, j)));
      setpair(YB, j, pkfma(G2, pairof(AB, j), pairof(YB, j)));
    }
  }

  // ---- store y (wave 0 only; both waves hold identical Y) ----
  if(wv == 0){
    if(f32in){
      float* out = (float*)outv;
      #pragma unroll
      for(int mt=0; mt<4; mt++){
        f32x4 vA, vB;
        #pragma unroll
        for(int i=0;i<4;i++){ vA[i] = YA[4*mt+i]; vB[i] = YB[4*mt+i]; }
        *(f32x4*)(out + rA*64 + mt*16 + g4) = vA;
        *(f32x4*)(out + rB*64 + mt*16 + g4) = vB;
      }
    } else {
      unsigned short* out = (unsigned short*)outv;
      #pragma unroll
      for(int mt=0; mt<4; mt++){
        u32x2 vA, vB;
        vA[0] = pk(YA[4*mt+0], YA[4*mt+1]);
        vA[1] = pk(YA[4*mt+2], YA[4*mt+3]);
        vB[0] = pk(YB[4*mt+0], YB[4*mt+1]);
        vB[1] = pk(YB[4*mt+2], YB[4*mt+3]);
        *(u32x2*)(out + rA*64 + mt*16 + g4) = vA;
        *(u32x2*)(out + rB*64 + mt*16 + g4) = vB;
      }
    }
  }
}

extern "C" void kernel_launch(void* const* d_in, const int* in_sizes, int n_in,
                              void* d_out, int out_size, void* d_ws, size_t ws_size,
                              hipStream_t stream){
  // 262144 rows / 32 rows per block (2 problems x 16), 128 threads = 8192 blocks
  hipLaunchKernelGGL(ode_kernel, dim3(8192), dim3(128), 0, stream,
                     d_in[0], d_in[1], d_in[2], d_in[3], d_in[4], d_in[5], d_out);
}

// Round 5
// 6981.257 us; speedup vs baseline: 1.2295x; 1.2295x over previous
//
#include <hip/hip_runtime.h>

#define NSTEP 64

typedef short bf8 __attribute__((ext_vector_type(8)));          // 8 x bf16 (4 VGPRs) MFMA A/B frag
typedef float f32x16 __attribute__((ext_vector_type(16)));
typedef float f32x4 __attribute__((ext_vector_type(4)));        // 16x16 MFMA C/D frag
typedef float f32x2 __attribute__((ext_vector_type(2)));
typedef unsigned int u32x4 __attribute__((ext_vector_type(4)));
typedef unsigned int u32x2 __attribute__((ext_vector_type(2)));

static __device__ __forceinline__ float asf(unsigned int u){ return __builtin_bit_cast(float, u); }
static __device__ __forceinline__ unsigned int asu(float f){ return __builtin_bit_cast(unsigned int, f); }

// fp32 pair -> packed bf16 dword (RNE, a in low 16)
#if defined(__has_builtin)
#if __has_builtin(__builtin_amdgcn_cvt_pk_bf16_f32)
#define HAVE_CVT_PK_BF16 1
#endif
#endif
#ifdef HAVE_CVT_PK_BF16
typedef __bf16 bf16x2_t __attribute__((ext_vector_type(2)));
static __device__ __forceinline__ unsigned int pk(float a, float b){
  bf16x2_t r = __builtin_amdgcn_cvt_pk_bf16_f32(a, b);
  return __builtin_bit_cast(unsigned int, r);
}
#else
static __device__ __forceinline__ unsigned int pk(float a, float b){
  unsigned int ua = asu(a); unsigned int ub = asu(b);
  ua += 0x7FFFu + ((ua >> 16) & 1u);
  ub += 0x7FFFu + ((ub >> 16) & 1u);
  return (ua >> 16) | (ub & 0xFFFF0000u);
}
#endif

// bf16 round of a f32 (matches what pk feeds the MFMA)
static __device__ __forceinline__ float bfr(float w){ return asf(pk(w, 0.0f) << 16); }

// packed 2xf32 math: compiler emits v_pk_* on gfx90a+
static __device__ __forceinline__ f32x2 pkfma(f32x2 a, f32x2 b, f32x2 c){
  return __builtin_elementwise_fma(a, b, c);
}

static __device__ __forceinline__ f32x2 pairof(const f32x16& v, int j){
  f32x2 r; r.x = v[2*j]; r.y = v[2*j+1]; return r;
}
static __device__ __forceinline__ void setpair(f32x16& v, int j, f32x2 p){
  v[2*j] = p.x; v[2*j+1] = p.y;
}

// scale 8 packed bf16 by s (one-time weight prep)
static __device__ __forceinline__ bf8 scale_bf8(bf8 w, float s){
  u32x4 u = __builtin_bit_cast(u32x4, w);
  u32x4 r;
  #pragma unroll
  for(int i=0;i<4;i++){
    float lo = asf(u[i] << 16) * s;
    float hi = asf(u[i] & 0xFFFF0000u) * s;
    r[i] = pk(lo, hi);
  }
  return __builtin_bit_cast(bf8, r);
}

#define MFMA16 __builtin_amdgcn_mfma_f32_16x16x32_bf16

// ---- k-permuted fragments (verified R3): ZERO cross-lane ops --------------
// Same bijection pi(g,j)->k on A and B leaves the MFMA result unchanged:
//   j<4 : k = t0_base + 4g + j ; j>=4: k = t1_base + 4g + (j-4)
// -> B-frag is the natural post-GEMM C-layout; weights loaded with the
//    matching column permutation (two 8B loads per frag).

// Shifted ELU on a 16x16 C-frag (4 elems): GEMM1 gives q = p*log2e (weights pre-scaled).
// h' = h+1 = max(q,0)*ln2 + exp2(min(q,0)); +1 shift compensated in b2' = b2 - rowsum(bf16 W2).
#define ELU2(A, H0, H1) { \
  f32x2 q0; q0.x=A[0]; q0.y=A[1]; \
  f32x2 q1; q1.x=A[2]; q1.y=A[3]; \
  f32x2 m0 = __builtin_elementwise_max(q0, Z2); \
  f32x2 n0 = __builtin_elementwise_min(q0, Z2); \
  f32x2 m1 = __builtin_elementwise_max(q1, Z2); \
  f32x2 n1 = __builtin_elementwise_min(q1, Z2); \
  f32x2 e0; e0.x=__builtin_amdgcn_exp2f(n0.x); e0.y=__builtin_amdgcn_exp2f(n0.y); \
  f32x2 e1; e1.x=__builtin_amdgcn_exp2f(n1.x); e1.y=__builtin_amdgcn_exp2f(n1.y); \
  f32x2 h0 = pkfma(m0, LN22, e0); \
  f32x2 h1 = pkfma(m1, LN22, e1); \
  H0 = pk(h0.x, h0.y); H1 = pk(h1.x, h1.y); \
}

// Chunk KT = 32 hidden units: GEMM1 tile pair (seeded from b1r regs) -> ELU ->
// GEMM2 k-step KT. KT==0 seeds p2 from b2r regs (no copies), else accumulates.
#define CHUNK0 { \
  f32x4 a0 = MFMA16(W1f[0][0], zf0, b1r[0], 0,0,0); \
  a0       = MFMA16(W1f[0][1], zf1, a0,     0,0,0); \
  f32x4 a1 = MFMA16(W1f[1][0], zf0, b1r[1], 0,0,0); \
  a1       = MFMA16(W1f[1][1], zf1, a1,     0,0,0); \
  unsigned int H00,H01,H10,H11; \
  ELU2(a0, H00, H01) \
  ELU2(a1, H10, H11) \
  u32x4 hu; hu[0]=H00; hu[1]=H01; hu[2]=H10; hu[3]=H11; \
  bf8 hf = __builtin_bit_cast(bf8, hu); \
  p2[0] = MFMA16(W2f[0][0], hf, b2r[0], 0,0,0); \
  p2[1] = MFMA16(W2f[1][0], hf, b2r[1], 0,0,0); \
  p2[2] = MFMA16(W2f[2][0], hf, b2r[2], 0,0,0); \
  p2[3] = MFMA16(W2f[3][0], hf, b2r[3], 0,0,0); \
}
#define CHUNKN(KT) { \
  f32x4 a0 = MFMA16(W1f[2*(KT)  ][0], zf0, b1r[2*(KT)],   0,0,0); \
  a0       = MFMA16(W1f[2*(KT)  ][1], zf1, a0,            0,0,0); \
  f32x4 a1 = MFMA16(W1f[2*(KT)+1][0], zf0, b1r[2*(KT)+1], 0,0,0); \
  a1       = MFMA16(W1f[2*(KT)+1][1], zf1, a1,            0,0,0); \
  unsigned int H00,H01,H10,H11; \
  ELU2(a0, H00, H01) \
  ELU2(a1, H10, H11) \
  u32x4 hu; hu[0]=H00; hu[1]=H01; hu[2]=H10; hu[3]=H11; \
  bf8 hf = __builtin_bit_cast(bf8, hu); \
  p2[0] = MFMA16(W2f[0][KT], hf, p2[0], 0,0,0); \
  p2[1] = MFMA16(W2f[1][KT], hf, p2[1], 0,0,0); \
  p2[2] = MFMA16(W2f[2][KT], hf, p2[2], 0,0,0); \
  p2[3] = MFMA16(W2f[3][KT], hf, p2[3], 0,0,0); \
}

// Block = 128 threads = 2 waves sharing one 16-row batch group (16x16x32 MFMA).
// Wave wv owns hidden [wv*128, wv*128+128). Per-stage DS = 4 writes + 4 reads only
// (bias seeds hoisted to regs). Exchange-read is fused with RK-accumulate and the
// next stage's z-pack, so no f32 c2 state survives -- only the packed zf (8 dw).
// Persistent regs ~216 -> fits 2 waves/SIMD under __launch_bounds__(128,2).
__global__ __launch_bounds__(128, 2) void ode_kernel(
    const void* __restrict__ xv,
    const void* __restrict__ tv,
    const void* __restrict__ W1v,
    const void* __restrict__ b1v,
    const void* __restrict__ W2v,
    const void* __restrict__ b2v,
    void* __restrict__ outv)
{
  __shared__ __align__(16) float b1s[256];
  __shared__ __align__(16) float b2s[64];
  __shared__ __align__(16) float xbuf[2][2][1024];   // [parity][wave][4 tiles * 64 lanes * 4 dw]

  const int tid = threadIdx.x;     // 0..127
  const int lid = tid & 63;        // lane in wave
  const int wv  = tid >> 6;        // wave in pair: hidden-half owner

  // ---- runtime input-dtype detection (wave-uniform; both waves identical) ----
  const unsigned int* w1u = (const unsigned int*)W1v;
  bool bad = false;
  #pragma unroll
  for(int i=0; i<2; i++){
    unsigned int d = w1u[i*64 + lid];
    unsigned int e0 = (d >> 7)  & 0xFFu;
    unsigned int e1 = (d >> 23) & 0xFFu;
    bad |= (e0 >= 125u) || (e1 >= 125u);
  }
  const bool f32in = (__ballot(bad) != 0ull);

  const float L2E = 1.4426950408889634f;

  // ---- biases to LDS (staging only): b1' = b1*log2e ; b2' = (b2 - rowsum(bf16 W2))*0.5 ----
  if(f32in){
    #pragma unroll
    for(int i=0; i<2; i++) b1s[tid + i*128] = ((const float*)b1v)[tid + i*128] * L2E;
  } else {
    #pragma unroll
    for(int i=0; i<2; i++)
      b1s[tid + i*128] = asf((unsigned int)((const unsigned short*)b1v)[tid + i*128] << 16) * L2E;
  }
  if(tid < 64){
    float ssum = 0.0f;
    if(f32in){
      const float* W2 = (const float*)W2v + tid*256;
      #pragma unroll 4
      for(int k=0; k<64; k++){
        f32x4 w4 = *(const f32x4*)(W2 + k*4);
        ssum += bfr(w4[0]) + bfr(w4[1]) + bfr(w4[2]) + bfr(w4[3]);
      }
    } else {
      const unsigned short* W2 = (const unsigned short*)W2v + tid*256;
      for(int k=0; k<256; k++) ssum += asf((unsigned int)W2[k] << 16);
    }
    float bb = f32in ? ((const float*)b2v)[tid]
                     : asf((unsigned int)((const unsigned short*)b2v)[tid] << 16);
    b2s[tid] = (bb - ssum) * 0.5f;   // both waves seed with half
  }
  __syncthreads();

  const int ln = lid & 15;         // MFMA m/n index = batch row within group
  const int g  = lid >> 4;         // lane group 0..3 (k-group / C row group)
  const int g4 = g * 4;
  const int rr = blockIdx.x * 16 + ln;   // global batch row

  const float t  = f32in ? ((const float*)tv)[0]
                         : asf((unsigned int)((const unsigned short*)tv)[0] << 16);
  const float dt  = t / (float)NSTEP;
  const float hdt = 0.5f * dt;
  const float gg  = dt * (1.0f/6.0f);
  const f32x2 DT2  = {dt, dt};
  const f32x2 HDT2 = {hdt, hdt};
  const f32x2 TWO2 = {2.0f, 2.0f};
  const f32x2 G2   = {gg, gg};
  const f32x2 LN22 = {0.6931471805599453f, 0.6931471805599453f};
  const f32x2 Z2   = {0.0f, 0.0f};

  // ---- bias seeds hoisted to registers (were 12 DS reads per stage) ----
  f32x4 b1r[8];   // GEMM1 C-seeds: tile tl of this wave's 128 hidden
  #pragma unroll
  for(int tl=0; tl<8; tl++) b1r[tl] = *(const f32x4*)&b1s[wv*128 + tl*16 + g4];
  f32x4 b2r[4];   // GEMM2 C-seeds (b2'/2)
  #pragma unroll
  for(int mt=0; mt<4; mt++) b2r[mt] = *(const f32x4*)&b2s[mt*16 + g4];

  // ---- weight A-fragments with the k-permutation; W1 pre-scaled by log2e ----
  bf8 W1f[8][2];   // [mtl: 16-row hidden tile within this wave's 128][ks: two 32-feat k-steps]
  bf8 W2f[4][4];   // [mt: 16-row out tile][kt: four 32-hidden k-steps of this wave's half]
  if(f32in){
    const float* W1 = (const float*)W1v;
    const float* W2 = (const float*)W2v;
    #pragma unroll
    for(int mtl=0; mtl<8; mtl++){
      #pragma unroll
      for(int ks=0; ks<2; ks++){
        const float* p = W1 + (wv*128 + mtl*16 + ln)*64 + ks*32 + g4;
        f32x4 a = *(const f32x4*)p;          // feats base+4g..+3   (slots j=0..3)
        f32x4 b = *(const f32x4*)(p + 16);   // feats base+16+4g..  (slots j=4..7)
        u32x4 u;
        u[0]=pk(a[0]*L2E, a[1]*L2E); u[1]=pk(a[2]*L2E, a[3]*L2E);
        u[2]=pk(b[0]*L2E, b[1]*L2E); u[3]=pk(b[2]*L2E, b[3]*L2E);
        W1f[mtl][ks] = __builtin_bit_cast(bf8, u);
      }
    }
    #pragma unroll
    for(int mt=0; mt<4; mt++){
      #pragma unroll
      for(int kt=0; kt<4; kt++){
        const float* p = W2 + (mt*16 + ln)*256 + wv*128 + kt*32 + g4;
        f32x4 a = *(const f32x4*)p;
        f32x4 b = *(const f32x4*)(p + 16);
        u32x4 u; u[0]=pk(a[0],a[1]); u[1]=pk(a[2],a[3]); u[2]=pk(b[0],b[1]); u[3]=pk(b[2],b[3]);
        W2f[mt][kt] = __builtin_bit_cast(bf8, u);
      }
    }
  } else {
    const unsigned short* W1 = (const unsigned short*)W1v;
    const unsigned short* W2 = (const unsigned short*)W2v;
    #pragma unroll
    for(int mtl=0; mtl<8; mtl++){
      #pragma unroll
      for(int ks=0; ks<2; ks++){
        const unsigned short* p = W1 + (wv*128 + mtl*16 + ln)*64 + ks*32 + g4;
        u32x2 lo = *(const u32x2*)p;         // feats base+4g..+3
        u32x2 hi = *(const u32x2*)(p + 16);  // feats base+16+4g..
        u32x4 u; u[0]=lo[0]; u[1]=lo[1]; u[2]=hi[0]; u[3]=hi[1];
        W1f[mtl][ks] = scale_bf8(__builtin_bit_cast(bf8, u), L2E);
      }
    }
    #pragma unroll
    for(int mt=0; mt<4; mt++){
      #pragma unroll
      for(int kt=0; kt<4; kt++){
        const unsigned short* p = W2 + (mt*16 + ln)*256 + wv*128 + kt*32 + g4;
        u32x2 lo = *(const u32x2*)p;
        u32x2 hi = *(const u32x2*)(p + 16);
        u32x4 u; u[0]=lo[0]; u[1]=lo[1]; u[2]=hi[0]; u[3]=hi[1];
        W2f[mt][kt] = __builtin_bit_cast(bf8, u);
      }
    }
  }

  // ---- state Y in 16x16 C-layout: Y[4*mt+i] = y[rr][mt*16 + g*4 + i], mt=0..3 ----
  f32x16 Y;
  if(f32in){
    const float* x = (const float*)xv;
    #pragma unroll
    for(int mt=0; mt<4; mt++){
      f32x4 v = *(const f32x4*)(x + rr*64 + mt*16 + g4);
      #pragma unroll
      for(int i=0;i<4;i++) Y[4*mt+i] = v[i];
    }
  } else {
    const unsigned short* x = (const unsigned short*)xv;
    #pragma unroll
    for(int mt=0; mt<4; mt++){
      u32x2 v = *(const u32x2*)(x + rr*64 + mt*16 + g4);
      Y[4*mt+0]=asf(v[0]<<16); Y[4*mt+1]=asf(v[0]&0xFFFF0000u);
      Y[4*mt+2]=asf(v[1]<<16); Y[4*mt+3]=asf(v[1]&0xFFFF0000u);
    }
  }

  // ---- packed z fragments (persist across stages; rebuilt in the fused loop) ----
  bf8 zf0, zf1;
  {
    u32x4 u0, u1;
    #pragma unroll
    for(int j=0;j<4;j++){
      f32x2 a = pairof(Y, j);     u0[j] = pk(a.x, a.y);
      f32x2 b = pairof(Y, j+4);   u1[j] = pk(b.x, b.y);
    }
    zf0 = __builtin_bit_cast(bf8, u0);
    zf1 = __builtin_bit_cast(bf8, u1);
  }

  int par = 0;

  #pragma unroll 1
  for(int step=0; step<NSTEP; step++){
    f32x16 A;   // RK4 accumulator: s0 writes it fully (A = k1)

    #pragma unroll
    for(int s=0; s<4; s++){
      f32x4 p2[4];
      CHUNK0 CHUNKN(1) CHUNKN(2) CHUNKN(3)

      // ---- exchange + RK-accumulate + next-stage z-pack, fused ----
      {
        float* my = &xbuf[par][wv][0];
        #pragma unroll
        for(int mt=0; mt<4; mt++)
          *(f32x4*)&my[(mt*64 + lid)*4] = p2[mt];
        __syncthreads();
        const float* prr = &xbuf[par][1-wv][0];
        u32x4 u0, u1;
        #pragma unroll
        for(int mt=0; mt<4; mt++){
          f32x4 v = *(const f32x4*)&prr[(mt*64 + lid)*4];
          f32x2 s0; s0.x = p2[mt][0]+v[0]; s0.y = p2[mt][1]+v[1];
          f32x2 s1; s1.x = p2[mt][2]+v[2]; s1.y = p2[mt][3]+v[3];
          // RK accumulate: s0: A=k; s1,s2: A+=2k; s3: A+=k
          if(s == 0){
            setpair(A, 2*mt, s0); setpair(A, 2*mt+1, s1);
          } else if(s == 3){
            setpair(A, 2*mt,   pairof(A, 2*mt)   + s0);
            setpair(A, 2*mt+1, pairof(A, 2*mt+1) + s1);
          } else {
            setpair(A, 2*mt,   pkfma(TWO2, s0, pairof(A, 2*mt)));
            setpair(A, 2*mt+1, pkfma(TWO2, s1, pairof(A, 2*mt+1)));
          }
          // next-stage z = Y + c_next * k  (no z after s3)
          if(s < 3){
            const f32x2 cn = (s==2) ? DT2 : HDT2;
            f32x2 z0 = pkfma(cn, s0, pairof(Y, 2*mt));
            f32x2 z1 = pkfma(cn, s1, pairof(Y, 2*mt+1));
            if(mt < 2){ u0[2*mt] = pk(z0.x, z0.y); u0[2*mt+1] = pk(z1.x, z1.y); }
            else      { u1[2*(mt-2)] = pk(z0.x, z0.y); u1[2*(mt-2)+1] = pk(z1.x, z1.y); }
          }
        }
        if(s < 3){
          zf0 = __builtin_bit_cast(bf8, u0);
          zf1 = __builtin_bit_cast(bf8, u1);
        }
        par ^= 1;
      }
    }

    // Y += dt/6 * A, then repack zf for next step's s0
    u32x4 u0, u1;
    #pragma unroll
    for(int j=0;j<8;j++){
      f32x2 y = pkfma(G2, pairof(A, j), pairof(Y, j));
      setpair(Y, j, y);
      if(j < 4) u0[j] = pk(y.x, y.y);
      else      u1[j-4] = pk(y.x, y.y);
    }
    zf0 = __builtin_bit_cast(bf8, u0);
    zf1 = __builtin_bit_cast(bf8, u1);
  }

  // ---- store y (wave 0 only; both waves hold identical Y) ----
  if(wv == 0){
    if(f32in){
      float* out = (float*)outv;
      #pragma unroll
      for(int mt=0; mt<4; mt++){
        f32x4 v;
        #pragma unroll
        for(int i=0;i<4;i++) v[i] = Y[4*mt+i];
        *(f32x4*)(out + rr*64 + mt*16 + g4) = v;
      }
    } else {
      unsigned short* out = (unsigned short*)outv;
      #pragma unroll
      for(int mt=0; mt<4; mt++){
        u32x2 v;
        v[0] = pk(Y[4*mt+0], Y[4*mt+1]);
        v[1] = pk(Y[4*mt+2], Y[4*mt+3]);
        *(u32x2*)(out + rr*64 + mt*16 + g4) = v;
      }
    }
  }
}

extern "C" void kernel_launch(void* const* d_in, const int* in_sizes, int n_in,
                              void* d_out, int out_size, void* d_ws, size_t ws_size,
                              hipStream_t stream){
  // 262144 rows / 16 rows per pair, 1 pair (128 threads) per block = 16384 blocks
  hipLaunchKernelGGL(ode_kernel, dim3(16384), dim3(128), 0, stream,
                     d_in[0], d_in[1], d_in[2], d_in[3], d_in[4], d_in[5], d_out);
}

// Round 6
// 6672.594 us; speedup vs baseline: 1.2864x; 1.0463x over previous
//
#include <hip/hip_runtime.h>

#define NSTEP 64

typedef short bf8 __attribute__((ext_vector_type(8)));          // 8 x bf16 (4 VGPRs) MFMA A/B frag
typedef float f32x16 __attribute__((ext_vector_type(16)));
typedef float f32x4 __attribute__((ext_vector_type(4)));        // 16x16 MFMA C/D frag
typedef float f32x2 __attribute__((ext_vector_type(2)));
typedef unsigned int u32x4 __attribute__((ext_vector_type(4)));
typedef unsigned int u32x2 __attribute__((ext_vector_type(2)));

static __device__ __forceinline__ float asf(unsigned int u){ return __builtin_bit_cast(float, u); }
static __device__ __forceinline__ unsigned int asu(float f){ return __builtin_bit_cast(unsigned int, f); }

// fp32 pair -> packed bf16 dword (RNE, a in low 16)
#if defined(__has_builtin)
#if __has_builtin(__builtin_amdgcn_cvt_pk_bf16_f32)
#define HAVE_CVT_PK_BF16 1
#endif
#endif
#ifdef HAVE_CVT_PK_BF16
typedef __bf16 bf16x2_t __attribute__((ext_vector_type(2)));
static __device__ __forceinline__ unsigned int pk(float a, float b){
  bf16x2_t r = __builtin_amdgcn_cvt_pk_bf16_f32(a, b);
  return __builtin_bit_cast(unsigned int, r);
}
#else
static __device__ __forceinline__ unsigned int pk(float a, float b){
  unsigned int ua = asu(a); unsigned int ub = asu(b);
  ua += 0x7FFFu + ((ua >> 16) & 1u);
  ub += 0x7FFFu + ((ub >> 16) & 1u);
  return (ua >> 16) | (ub & 0xFFFF0000u);
}
#endif

// bf16 round of a f32 (matches what pk feeds the MFMA)
static __device__ __forceinline__ float bfr(float w){ return asf(pk(w, 0.0f) << 16); }

// packed 2xf32 math: compiler emits v_pk_* on gfx90a+
static __device__ __forceinline__ f32x2 pkfma(f32x2 a, f32x2 b, f32x2 c){
  return __builtin_elementwise_fma(a, b, c);
}

static __device__ __forceinline__ f32x2 pairof(const f32x16& v, int j){
  f32x2 r; r.x = v[2*j]; r.y = v[2*j+1]; return r;
}
static __device__ __forceinline__ void setpair(f32x16& v, int j, f32x2 p){
  v[2*j] = p.x; v[2*j+1] = p.y;
}

// scale 8 packed bf16 by s (one-time weight prep)
static __device__ __forceinline__ bf8 scale_bf8(bf8 w, float s){
  u32x4 u = __builtin_bit_cast(u32x4, w);
  u32x4 r;
  #pragma unroll
  for(int i=0;i<4;i++){
    float lo = asf(u[i] << 16) * s;
    float hi = asf(u[i] & 0xFFFF0000u) * s;
    r[i] = pk(lo, hi);
  }
  return __builtin_bit_cast(bf8, r);
}

#define MFMA16 __builtin_amdgcn_mfma_f32_16x16x32_bf16

// ---- k-permuted fragments (verified R3): ZERO cross-lane ops --------------
// Same bijection pi(g,j)->k on A and B leaves the MFMA result unchanged:
//   j<4 : k = t0_base + 4g + j ; j>=4: k = t1_base + 4g + (j-4)
// -> B-frag is the natural post-GEMM C-layout; weights loaded with the
//    matching column permutation (two 8B loads per frag).

// Shifted ELU on a 16x16 C-frag (4 elems): GEMM1 gives q = p*log2e (weights pre-scaled).
// h' = h+1 = max(q,0)*ln2 + exp2(min(q,0)); +1 shift compensated in b2' = b2 - rowsum(bf16 W2).
#define ELU2(A, H0, H1) { \
  f32x2 q0; q0.x=A[0]; q0.y=A[1]; \
  f32x2 q1; q1.x=A[2]; q1.y=A[3]; \
  f32x2 m0 = __builtin_elementwise_max(q0, Z2); \
  f32x2 n0 = __builtin_elementwise_min(q0, Z2); \
  f32x2 m1 = __builtin_elementwise_max(q1, Z2); \
  f32x2 n1 = __builtin_elementwise_min(q1, Z2); \
  f32x2 e0; e0.x=__builtin_amdgcn_exp2f(n0.x); e0.y=__builtin_amdgcn_exp2f(n0.y); \
  f32x2 e1; e1.x=__builtin_amdgcn_exp2f(n1.x); e1.y=__builtin_amdgcn_exp2f(n1.y); \
  f32x2 h0 = pkfma(m0, LN22, e0); \
  f32x2 h1 = pkfma(m1, LN22, e1); \
  H0 = pk(h0.x, h0.y); H1 = pk(h1.x, h1.y); \
}

// GEMM1 tile pair KT (seeded from b1r regs) -> ELU -> packed h fragment HF
#define GEMM1ELU(KT, HF) \
  bf8 HF; { \
    f32x4 a0 = MFMA16(W1f[2*(KT)  ][0], zf0, b1r[2*(KT)],   0,0,0); \
    a0       = MFMA16(W1f[2*(KT)  ][1], zf1, a0,            0,0,0); \
    f32x4 a1 = MFMA16(W1f[2*(KT)+1][0], zf0, b1r[2*(KT)+1], 0,0,0); \
    a1       = MFMA16(W1f[2*(KT)+1][1], zf1, a1,            0,0,0); \
    unsigned int H00,H01,H10,H11; \
    ELU2(a0, H00, H01) \
    ELU2(a1, H10, H11) \
    u32x4 hu; hu[0]=H00; hu[1]=H01; hu[2]=H10; hu[3]=H11; \
    HF = __builtin_bit_cast(bf8, hu); \
  }

// Block = 128 threads = 2 waves sharing one 16-row batch group (16x16x32 MFMA).
// Wave wv owns hidden [wv*128, wv*128+128). Per-stage DS = 4 writes + 4 reads
// (bias seeds in regs). Stage schedule: [setprio 1] GEMM1+ELU all chunks ->
// GEMM2 per out-tile with EARLY ds_write (3/4 writes retire under MFMA)
// [setprio 0] -> barrier -> fused read+RK+z-pack (s3 also folds the Y-update).
__global__ __launch_bounds__(128, 2) void ode_kernel(
    const void* __restrict__ xv,
    const void* __restrict__ tv,
    const void* __restrict__ W1v,
    const void* __restrict__ b1v,
    const void* __restrict__ W2v,
    const void* __restrict__ b2v,
    void* __restrict__ outv)
{
  __shared__ __align__(16) float b1s[256];
  __shared__ __align__(16) float b2s[64];
  __shared__ __align__(16) float xbuf[2][2][1024];   // [parity][wave][4 tiles * 64 lanes * 4 dw]

  const int tid = threadIdx.x;     // 0..127
  const int lid = tid & 63;        // lane in wave
  const int wv  = tid >> 6;        // wave in pair: hidden-half owner

  // ---- runtime input-dtype detection (wave-uniform; both waves identical) ----
  const unsigned int* w1u = (const unsigned int*)W1v;
  bool bad = false;
  #pragma unroll
  for(int i=0; i<2; i++){
    unsigned int d = w1u[i*64 + lid];
    unsigned int e0 = (d >> 7)  & 0xFFu;
    unsigned int e1 = (d >> 23) & 0xFFu;
    bad |= (e0 >= 125u) || (e1 >= 125u);
  }
  const bool f32in = (__ballot(bad) != 0ull);

  const float L2E = 1.4426950408889634f;

  // ---- biases to LDS (staging only): b1' = b1*log2e ; b2' = (b2 - rowsum(bf16 W2))*0.5 ----
  if(f32in){
    #pragma unroll
    for(int i=0; i<2; i++) b1s[tid + i*128] = ((const float*)b1v)[tid + i*128] * L2E;
  } else {
    #pragma unroll
    for(int i=0; i<2; i++)
      b1s[tid + i*128] = asf((unsigned int)((const unsigned short*)b1v)[tid + i*128] << 16) * L2E;
  }
  if(tid < 64){
    float ssum = 0.0f;
    if(f32in){
      const float* W2 = (const float*)W2v + tid*256;
      #pragma unroll 4
      for(int k=0; k<64; k++){
        f32x4 w4 = *(const f32x4*)(W2 + k*4);
        ssum += bfr(w4[0]) + bfr(w4[1]) + bfr(w4[2]) + bfr(w4[3]);
      }
    } else {
      const unsigned short* W2 = (const unsigned short*)W2v + tid*256;
      for(int k=0; k<256; k++) ssum += asf((unsigned int)W2[k] << 16);
    }
    float bb = f32in ? ((const float*)b2v)[tid]
                     : asf((unsigned int)((const unsigned short*)b2v)[tid] << 16);
    b2s[tid] = (bb - ssum) * 0.5f;   // both waves seed with half
  }
  __syncthreads();

  const int ln = lid & 15;         // MFMA m/n index = batch row within group
  const int g  = lid >> 4;         // lane group 0..3 (k-group / C row group)
  const int g4 = g * 4;
  const int rr = blockIdx.x * 16 + ln;   // global batch row

  const float t  = f32in ? ((const float*)tv)[0]
                         : asf((unsigned int)((const unsigned short*)tv)[0] << 16);
  const float dt  = t / (float)NSTEP;
  const float hdt = 0.5f * dt;
  const float gg  = dt * (1.0f/6.0f);
  const f32x2 DT2  = {dt, dt};
  const f32x2 HDT2 = {hdt, hdt};
  const f32x2 TWO2 = {2.0f, 2.0f};
  const f32x2 G2   = {gg, gg};
  const f32x2 LN22 = {0.6931471805599453f, 0.6931471805599453f};
  const f32x2 Z2   = {0.0f, 0.0f};

  // ---- bias seeds hoisted to registers ----
  f32x4 b1r[8];   // GEMM1 C-seeds: tile tl of this wave's 128 hidden
  #pragma unroll
  for(int tl=0; tl<8; tl++) b1r[tl] = *(const f32x4*)&b1s[wv*128 + tl*16 + g4];
  f32x4 b2r[4];   // GEMM2 C-seeds (b2'/2)
  #pragma unroll
  for(int mt=0; mt<4; mt++) b2r[mt] = *(const f32x4*)&b2s[mt*16 + g4];

  // ---- weight A-fragments with the k-permutation; W1 pre-scaled by log2e ----
  bf8 W1f[8][2];   // [mtl: 16-row hidden tile within this wave's 128][ks: two 32-feat k-steps]
  bf8 W2f[4][4];   // [mt: 16-row out tile][kt: four 32-hidden k-steps of this wave's half]
  if(f32in){
    const float* W1 = (const float*)W1v;
    const float* W2 = (const float*)W2v;
    #pragma unroll
    for(int mtl=0; mtl<8; mtl++){
      #pragma unroll
      for(int ks=0; ks<2; ks++){
        const float* p = W1 + (wv*128 + mtl*16 + ln)*64 + ks*32 + g4;
        f32x4 a = *(const f32x4*)p;          // feats base+4g..+3   (slots j=0..3)
        f32x4 b = *(const f32x4*)(p + 16);   // feats base+16+4g..  (slots j=4..7)
        u32x4 u;
        u[0]=pk(a[0]*L2E, a[1]*L2E); u[1]=pk(a[2]*L2E, a[3]*L2E);
        u[2]=pk(b[0]*L2E, b[1]*L2E); u[3]=pk(b[2]*L2E, b[3]*L2E);
        W1f[mtl][ks] = __builtin_bit_cast(bf8, u);
      }
    }
    #pragma unroll
    for(int mt=0; mt<4; mt++){
      #pragma unroll
      for(int kt=0; kt<4; kt++){
        const float* p = W2 + (mt*16 + ln)*256 + wv*128 + kt*32 + g4;
        f32x4 a = *(const f32x4*)p;
        f32x4 b = *(const f32x4*)(p + 16);
        u32x4 u; u[0]=pk(a[0],a[1]); u[1]=pk(a[2],a[3]); u[2]=pk(b[0],b[1]); u[3]=pk(b[2],b[3]);
        W2f[mt][kt] = __builtin_bit_cast(bf8, u);
      }
    }
  } else {
    const unsigned short* W1 = (const unsigned short*)W1v;
    const unsigned short* W2 = (const unsigned short*)W2v;
    #pragma unroll
    for(int mtl=0; mtl<8; mtl++){
      #pragma unroll
      for(int ks=0; ks<2; ks++){
        const unsigned short* p = W1 + (wv*128 + mtl*16 + ln)*64 + ks*32 + g4;
        u32x2 lo = *(const u32x2*)p;         // feats base+4g..+3
        u32x2 hi = *(const u32x2*)(p + 16);  // feats base+16+4g..
        u32x4 u; u[0]=lo[0]; u[1]=lo[1]; u[2]=hi[0]; u[3]=hi[1];
        W1f[mtl][ks] = scale_bf8(__builtin_bit_cast(bf8, u), L2E);
      }
    }
    #pragma unroll
    for(int mt=0; mt<4; mt++){
      #pragma unroll
      for(int kt=0; kt<4; kt++){
        const unsigned short* p = W2 + (mt*16 + ln)*256 + wv*128 + kt*32 + g4;
        u32x2 lo = *(const u32x2*)p;
        u32x2 hi = *(const u32x2*)(p + 16);
        u32x4 u; u[0]=lo[0]; u[1]=lo[1]; u[2]=hi[0]; u[3]=hi[1];
        W2f[mt][kt] = __builtin_bit_cast(bf8, u);
      }
    }
  }

  // ---- state Y in 16x16 C-layout: Y[4*mt+i] = y[rr][mt*16 + g*4 + i], mt=0..3 ----
  f32x16 Y;
  if(f32in){
    const float* x = (const float*)xv;
    #pragma unroll
    for(int mt=0; mt<4; mt++){
      f32x4 v = *(const f32x4*)(x + rr*64 + mt*16 + g4);
      #pragma unroll
      for(int i=0;i<4;i++) Y[4*mt+i] = v[i];
    }
  } else {
    const unsigned short* x = (const unsigned short*)xv;
    #pragma unroll
    for(int mt=0; mt<4; mt++){
      u32x2 v = *(const u32x2*)(x + rr*64 + mt*16 + g4);
      Y[4*mt+0]=asf(v[0]<<16); Y[4*mt+1]=asf(v[0]&0xFFFF0000u);
      Y[4*mt+2]=asf(v[1]<<16); Y[4*mt+3]=asf(v[1]&0xFFFF0000u);
    }
  }

  // ---- packed z fragments (persist across stages; rebuilt in the fused loop) ----
  bf8 zf0, zf1;
  {
    u32x4 u0, u1;
    #pragma unroll
    for(int j=0;j<4;j++){
      f32x2 a = pairof(Y, j);     u0[j] = pk(a.x, a.y);
      f32x2 b = pairof(Y, j+4);   u1[j] = pk(b.x, b.y);
    }
    zf0 = __builtin_bit_cast(bf8, u0);
    zf1 = __builtin_bit_cast(bf8, u1);
  }

  int par = 0;

  #pragma unroll 1
  for(int step=0; step<NSTEP; step++){
    f32x16 A;   // RK4 accumulator: s0 writes it fully (A = k1)

    #pragma unroll
    for(int s=0; s<4; s++){
      __builtin_amdgcn_s_setprio(1);
      // ---- GEMM1 + ELU, all 4 chunks (hf frags held live) ----
      GEMM1ELU(0, hf0) GEMM1ELU(1, hf1) GEMM1ELU(2, hf2) GEMM1ELU(3, hf3)

      // ---- GEMM2 per out-tile, early ds_write (retires under later MFMA) ----
      float* my = &xbuf[par][wv][0];
      f32x4 p2[4];
      #pragma unroll
      for(int mt=0; mt<4; mt++){
        f32x4 p = MFMA16(W2f[mt][0], hf0, b2r[mt], 0,0,0);
        p       = MFMA16(W2f[mt][1], hf1, p,       0,0,0);
        p       = MFMA16(W2f[mt][2], hf2, p,       0,0,0);
        p       = MFMA16(W2f[mt][3], hf3, p,       0,0,0);
        p2[mt] = p;
        *(f32x4*)&my[(mt*64 + lid)*4] = p;
      }
      __builtin_amdgcn_s_setprio(0);
      __syncthreads();

      // ---- fused: read partner + RK-accumulate + z-pack (s3 folds Y-update) ----
      {
        const float* prr = &xbuf[par][1-wv][0];
        u32x4 u0, u1;
        #pragma unroll
        for(int mt=0; mt<4; mt++){
          f32x4 v = *(const f32x4*)&prr[(mt*64 + lid)*4];
          f32x2 s0; s0.x = p2[mt][0]+v[0]; s0.y = p2[mt][1]+v[1];
          f32x2 s1; s1.x = p2[mt][2]+v[2]; s1.y = p2[mt][3]+v[3];
          f32x2 z0, z1;
          if(s == 0){
            setpair(A, 2*mt, s0); setpair(A, 2*mt+1, s1);
            z0 = pkfma(HDT2, s0, pairof(Y, 2*mt));
            z1 = pkfma(HDT2, s1, pairof(Y, 2*mt+1));
          } else if(s == 1){
            setpair(A, 2*mt,   pkfma(TWO2, s0, pairof(A, 2*mt)));
            setpair(A, 2*mt+1, pkfma(TWO2, s1, pairof(A, 2*mt+1)));
            z0 = pkfma(HDT2, s0, pairof(Y, 2*mt));
            z1 = pkfma(HDT2, s1, pairof(Y, 2*mt+1));
          } else if(s == 2){
            setpair(A, 2*mt,   pkfma(TWO2, s0, pairof(A, 2*mt)));
            setpair(A, 2*mt+1, pkfma(TWO2, s1, pairof(A, 2*mt+1)));
            z0 = pkfma(DT2, s0, pairof(Y, 2*mt));
            z1 = pkfma(DT2, s1, pairof(Y, 2*mt+1));
          } else {
            // s3: finish A, update Y, pack zf from new Y (next step's s0 input)
            f32x2 a0f = pairof(A, 2*mt)   + s0;
            f32x2 a1f = pairof(A, 2*mt+1) + s1;
            z0 = pkfma(G2, a0f, pairof(Y, 2*mt));
            z1 = pkfma(G2, a1f, pairof(Y, 2*mt+1));
            setpair(Y, 2*mt,   z0);
            setpair(Y, 2*mt+1, z1);
          }
          if(mt < 2){ u0[2*mt] = pk(z0.x, z0.y); u0[2*mt+1] = pk(z1.x, z1.y); }
          else      { u1[2*(mt-2)] = pk(z0.x, z0.y); u1[2*(mt-2)+1] = pk(z1.x, z1.y); }
        }
        zf0 = __builtin_bit_cast(bf8, u0);
        zf1 = __builtin_bit_cast(bf8, u1);
        par ^= 1;
      }
    }
  }

  // ---- store y (wave 0 only; both waves hold identical Y) ----
  if(wv == 0){
    if(f32in){
      float* out = (float*)outv;
      #pragma unroll
      for(int mt=0; mt<4; mt++){
        f32x4 v;
        #pragma unroll
        for(int i=0;i<4;i++) v[i] = Y[4*mt+i];
        *(f32x4*)(out + rr*64 + mt*16 + g4) = v;
      }
    } else {
      unsigned short* out = (unsigned short*)outv;
      #pragma unroll
      for(int mt=0; mt<4; mt++){
        u32x2 v;
        v[0] = pk(Y[4*mt+0], Y[4*mt+1]);
        v[1] = pk(Y[4*mt+2], Y[4*mt+3]);
        *(u32x2*)(out + rr*64 + mt*16 + g4) = v;
      }
    }
  }
}

extern "C" void kernel_launch(void* const* d_in, const int* in_sizes, int n_in,
                              void* d_out, int out_size, void* d_ws, size_t ws_size,
                              hipStream_t stream){
  // 262144 rows / 16 rows per pair, 1 pair (128 threads) per block = 16384 blocks
  hipLaunchKernelGGL(ode_kernel, dim3(16384), dim3(128), 0, stream,
                     d_in[0], d_in[1], d_in[2], d_in[3], d_in[4], d_in[5], d_out);
}